// Round 1
// baseline (1907.950 us; speedup 1.0000x reference)
//
#include <hip/hip_runtime.h>
#include <math.h>

#define N_NODES 40000
#define N_EDGES 640000
#define DIM     128
#define HEADS   8
#define DHEAD   16
#define LAYERS  3
#define IN_DIM  64
#define FF_DIM  218
#define BN_EPS  1e-5f
#define NEG_SLOPE 0.2f

// ---------------------------------------------------------------- CSR build
__global__ void hist_kernel(const int* __restrict__ dst, int* __restrict__ counts) {
    int e = blockIdx.x * blockDim.x + threadIdx.x;
    if (e < N_EDGES) atomicAdd(&counts[dst[e]], 1);
}

// single-block exclusive scan of counts[n] -> indptr[n+1]
__global__ void scan_kernel(const int* __restrict__ counts, int* __restrict__ indptr, int n) {
    __shared__ int temp[1024];
    __shared__ int carry;
    int tid = threadIdx.x;
    if (tid == 0) carry = 0;
    __syncthreads();
    for (int base = 0; base < n; base += 1024) {
        int v = (base + tid < n) ? counts[base + tid] : 0;
        temp[tid] = v;
        __syncthreads();
        for (int offs = 1; offs < 1024; offs <<= 1) {
            int t = (tid >= offs) ? temp[tid - offs] : 0;
            __syncthreads();
            temp[tid] += t;
            __syncthreads();
        }
        int incl = temp[tid];
        if (base + tid < n) indptr[base + tid] = carry + incl - v;
        __syncthreads();
        if (tid == 0) carry += temp[1023];
        __syncthreads();
    }
    if (tid == 0) indptr[n] = carry;
}

__global__ void scatter_kernel(const int* __restrict__ dst, int* __restrict__ cursor,
                               int* __restrict__ eids) {
    int e = blockIdx.x * blockDim.x + threadIdx.x;
    if (e < N_EDGES) {
        int pos = atomicAdd(&cursor[dst[e]], 1);
        eids[pos] = e;
    }
}

// ---------------------------------------------------------------- GEMM (fp32)
// C[M,N] = A[M,K] @ B[K,N] (+bias) (+res) (relu?)
__global__ __launch_bounds__(256) void gemm_kernel(
    const float* __restrict__ A, int lda,
    const float* __restrict__ B, int ldb,
    const float* __restrict__ bias,
    const float* __restrict__ res, int ldres,
    float* __restrict__ C, int ldc,
    int M, int N, int K, int relu)
{
    __shared__ float As[16][64];
    __shared__ float Bs[16][64];
    int tid = threadIdx.x;
    int tx = tid & 15, ty = tid >> 4;
    int row0 = blockIdx.y * 64;
    int col0 = blockIdx.x * 64;
    float acc[4][4] = {};
    for (int k0 = 0; k0 < K; k0 += 16) {
        {   // A tile: 64 rows x 16 k
            int m  = tid >> 2;
            int kk = (tid & 3) << 2;
            int gr = row0 + m;
            #pragma unroll
            for (int i = 0; i < 4; i++) {
                int gk = k0 + kk + i;
                As[kk + i][m] = (gr < M && gk < K) ? A[(size_t)gr * lda + gk] : 0.f;
            }
        }
        {   // B tile: 16 k x 64 n
            int n  = tid & 63;
            int kb = tid >> 6;
            #pragma unroll
            for (int j = 0; j < 4; j++) {
                int k = kb * 4 + j;
                int gk = k0 + k;
                int gn = col0 + n;
                Bs[k][n] = (gk < K && gn < N) ? B[(size_t)gk * ldb + gn] : 0.f;
            }
        }
        __syncthreads();
        #pragma unroll
        for (int k = 0; k < 16; k++) {
            float a[4], b[4];
            #pragma unroll
            for (int i = 0; i < 4; i++) a[i] = As[k][ty * 4 + i];
            #pragma unroll
            for (int j = 0; j < 4; j++) b[j] = Bs[k][tx * 4 + j];
            #pragma unroll
            for (int i = 0; i < 4; i++)
                #pragma unroll
                for (int j = 0; j < 4; j++)
                    acc[i][j] = fmaf(a[i], b[j], acc[i][j]);
        }
        __syncthreads();
    }
    #pragma unroll
    for (int i = 0; i < 4; i++) {
        int r = row0 + ty * 4 + i;
        if (r >= M) continue;
        #pragma unroll
        for (int j = 0; j < 4; j++) {
            int c = col0 + tx * 4 + j;
            if (c >= N) continue;
            float v = acc[i][j];
            if (bias) v += bias[c];
            if (res)  v += res[(size_t)r * ldres + c];
            if (relu) v = fmaxf(v, 0.f);
            C[(size_t)r * ldc + c] = v;
        }
    }
}

// ---------------------------------------------------------------- GAT pieces
// el[n,h] = sum_d feat[n,h,d]*al[h,d]; er likewise
__global__ void eler_kernel(const float* __restrict__ feat,
                            const float* __restrict__ al, const float* __restrict__ ar,
                            float* __restrict__ el, float* __restrict__ er) {
    int i = blockIdx.x * blockDim.x + threadIdx.x;
    if (i >= N_NODES * HEADS) return;
    int n = i >> 3, h = i & 7;
    const float* f = feat + (size_t)n * DIM + h * DHEAD;
    float sl = 0.f, sr = 0.f;
    #pragma unroll
    for (int d = 0; d < DHEAD; d++) {
        float fv = f[d];
        sl = fmaf(fv, al[h * DHEAD + d], sl);
        sr = fmaf(fv, ar[h * DHEAD + d], sr);
    }
    el[i] = sl;
    er[i] = sr;
}

// e[e,h] = leaky_relu(el[src]+er[dst])
__global__ void edge_e_kernel(const int* __restrict__ src, const int* __restrict__ dst,
                              const float* __restrict__ el, const float* __restrict__ er,
                              float* __restrict__ ebuf) {
    int i = blockIdx.x * blockDim.x + threadIdx.x;
    if (i >= N_EDGES * HEADS) return;
    int e = i >> 3, h = i & 7;
    float v = el[src[e] * HEADS + h] + er[dst[e] * HEADS + h];
    ebuf[i] = v > 0.f ? v : NEG_SLOPE * v;
}

// per-dst-node segment softmax + weighted aggregate + skip + bias
__global__ __launch_bounds__(128) void gat_aggregate_kernel(
    const float* __restrict__ feat, const float* __restrict__ ebuf,
    const int* __restrict__ indptr, const int* __restrict__ eids,
    const int* __restrict__ src,
    const float* __restrict__ h_in, int ldh,
    const float* __restrict__ bias,
    float* __restrict__ outp)
{
    int n = blockIdx.x;
    int t = threadIdx.x;           // 128 threads: t = h*16 + dh
    __shared__ float m_s[HEADS], inv_s[HEADS];
    int beg = indptr[n], end = indptr[n + 1];
    if (t < HEADS) {
        float m = -INFINITY;
        for (int i = beg; i < end; i++) {
            float ev = ebuf[(size_t)eids[i] * HEADS + t];
            m = fmaxf(m, ev);
        }
        float s = 0.f;
        for (int i = beg; i < end; i++)
            s += expf(ebuf[(size_t)eids[i] * HEADS + t] - m);
        m_s[t] = m;
        inv_s[t] = (s > 0.f) ? 1.f / s : 0.f;
    }
    __syncthreads();
    int h = t >> 4;
    float m = m_s[h], inv = inv_s[h];
    float acc = 0.f;
    for (int i = beg; i < end; i++) {
        int eid = eids[i];
        int sn = src[eid];
        float a = expf(ebuf[(size_t)eid * HEADS + h] - m) * inv;
        acc = fmaf(a, feat[(size_t)sn * DIM + t], acc);
    }
    outp[(size_t)n * DIM + t] = h_in[(size_t)n * ldh + t] + acc + bias[t];
}

// ---------------------------------------------------------------- BatchNorm
// stats: [0..127]=sum, [128..255]=sumsq
__global__ __launch_bounds__(128) void bn_stats_kernel(const float* __restrict__ x, int ldx,
                                                       int M, float* __restrict__ stats) {
    int c = threadIdx.x;                 // 128 cols
    int r0 = blockIdx.x * 128;
    int r1 = min(r0 + 128, M);
    float s = 0.f, sq = 0.f;
    for (int r = r0; r < r1; r++) {
        float v = x[(size_t)r * ldx + c];
        s += v;
        sq = fmaf(v, v, sq);
    }
    atomicAdd(&stats[c], s);
    atomicAdd(&stats[DIM + c], sq);
}

__global__ void bn_apply_kernel(const float* __restrict__ x, int ldin,
                                float* __restrict__ y, int ldout,
                                const float* __restrict__ g, const float* __restrict__ b,
                                const float* __restrict__ stats, int M) {
    int i = blockIdx.x * blockDim.x + threadIdx.x;
    if (i >= M * DIM) return;
    int r = i >> 7, c = i & 127;
    float mu  = stats[c] * (1.f / N_NODES);
    float var = stats[DIM + c] * (1.f / N_NODES) - mu * mu;
    float v = x[(size_t)r * ldin + c];
    y[(size_t)r * ldout + c] = fmaf(g[c] * rsqrtf(var + BN_EPS), v - mu, b[c]);
}

// ---------------------------------------------------------------- decision head
// out[n] = sum_c relu(bn(z[n,c])) * W2[c]   — one wave per node
__global__ __launch_bounds__(256) void decide_kernel(
    const float* __restrict__ z, const float* __restrict__ stats,
    const float* __restrict__ g, const float* __restrict__ b,
    const float* __restrict__ W2, float* __restrict__ outp, int M)
{
    int wid = threadIdx.x >> 6, lane = threadIdx.x & 63;
    int n = blockIdx.x * 4 + wid;
    if (n >= M) return;
    float acc = 0.f;
    for (int c = lane; c < DIM; c += 64) {
        float mu  = stats[c] * (1.f / N_NODES);
        float var = stats[DIM + c] * (1.f / N_NODES) - mu * mu;
        float v = fmaf(g[c] * rsqrtf(var + BN_EPS), z[(size_t)n * DIM + c] - mu, b[c]);
        v = fmaxf(v, 0.f);
        acc = fmaf(v, W2[c], acc);
    }
    #pragma unroll
    for (int offs = 32; offs > 0; offs >>= 1)
        acc += __shfl_down(acc, offs);
    if (lane == 0) outp[n] = acc;
}

// ---------------------------------------------------------------- launch
extern "C" void kernel_launch(void* const* d_in, const int* in_sizes, int n_in,
                              void* d_out, int out_size, void* d_ws, size_t ws_size,
                              hipStream_t stream)
{
    const float* x      = (const float*)d_in[0];
    const int*   src    = (const int*)  d_in[1];
    const int*   dst    = (const int*)  d_in[2];
    const float* W_emb  = (const float*)d_in[3];
    const float* b_emb  = (const float*)d_in[4];
    const float* gat_W  = (const float*)d_in[5];
    const float* attn_l = (const float*)d_in[6];
    const float* attn_r = (const float*)d_in[7];
    const float* gat_b  = (const float*)d_in[8];
    const float* bn1_g  = (const float*)d_in[9];
    const float* bn1_b  = (const float*)d_in[10];
    const float* ff_W1  = (const float*)d_in[11];
    const float* ff_b1  = (const float*)d_in[12];
    const float* ff_W2  = (const float*)d_in[13];
    const float* ff_b2  = (const float*)d_in[14];
    const float* bn2_g  = (const float*)d_in[15];
    const float* bn2_b  = (const float*)d_in[16];
    const float* dec_W1 = (const float*)d_in[17];
    const float* dec_bn_g = (const float*)d_in[18];
    const float* dec_bn_b = (const float*)d_in[19];
    const float* dec_W2 = (const float*)d_in[20];
    float* outp = (float*)d_out;

    char* ws = (char*)d_ws;
    size_t off = 0;
    auto alloc = [&](size_t bytes) -> void* {
        void* p = ws + off;
        off += (bytes + 255) & ~(size_t)255;
        return p;
    };
    float* xs    = (float*)alloc((size_t)N_NODES * 512 * 4);   // concat buffer [N, 4*128]
    float* feat  = (float*)alloc((size_t)N_NODES * DIM * 4);   // also reused for dec z
    float* el    = (float*)alloc((size_t)N_NODES * HEADS * 4);
    float* er    = (float*)alloc((size_t)N_NODES * HEADS * 4);
    float* ebuf  = (float*)alloc((size_t)N_EDGES * HEADS * 4);
    float* y1    = (float*)alloc((size_t)N_NODES * FF_DIM * 4);
    float* bt    = (float*)alloc((size_t)N_NODES * DIM * 4);
    float* stats = (float*)alloc(2 * DIM * 4);
    int*   counts= (int*)  alloc((size_t)N_NODES * 4);
    int*   indptr= (int*)  alloc((size_t)(N_NODES + 1) * 4);
    int*   cursor= (int*)  alloc((size_t)N_NODES * 4);
    int*   eids  = (int*)  alloc((size_t)N_EDGES * 4);
    (void)ws_size; (void)in_sizes; (void)n_in; (void)out_size;

    auto launch_gemm = [&](const float* A, int lda, const float* B, int ldb,
                           const float* bias, const float* res, int ldres,
                           float* C, int ldc, int M, int N, int K, int relu) {
        dim3 grid((N + 63) / 64, (M + 63) / 64);
        gemm_kernel<<<grid, 256, 0, stream>>>(A, lda, B, ldb, bias, res, ldres,
                                              C, ldc, M, N, K, relu);
    };

    // ---- CSR build (deterministic work each call)
    hipMemsetAsync(counts, 0, N_NODES * 4, stream);
    hist_kernel<<<(N_EDGES + 255) / 256, 256, 0, stream>>>(dst, counts);
    scan_kernel<<<1, 1024, 0, stream>>>(counts, indptr, N_NODES);
    hipMemcpyAsync(cursor, indptr, N_NODES * 4, hipMemcpyDeviceToDevice, stream);
    scatter_kernel<<<(N_EDGES + 255) / 256, 256, 0, stream>>>(dst, cursor, eids);

    // ---- embed: xs[:, 0:128] = x @ W_emb + b_emb
    launch_gemm(x, IN_DIM, W_emb, DIM, b_emb, nullptr, 0, xs, 512,
                N_NODES, DIM, IN_DIM, 0);

    for (int l = 0; l < LAYERS; l++) {
        const float* h_cur = xs + (size_t)l * DIM;           // ld = 512
        // feat = h @ gat_W[l]
        launch_gemm(h_cur, 512, gat_W + (size_t)l * DIM * DIM, DIM,
                    nullptr, nullptr, 0, feat, DIM, N_NODES, DIM, DIM, 0);
        // el/er
        eler_kernel<<<(N_NODES * HEADS + 255) / 256, 256, 0, stream>>>(
            feat, attn_l + l * DIM, attn_r + l * DIM, el, er);
        // e per edge
        edge_e_kernel<<<(N_EDGES * HEADS + 255) / 256, 256, 0, stream>>>(
            src, dst, el, er, ebuf);
        // aggregate (softmax + msg + skip + bias) -> bt
        gat_aggregate_kernel<<<N_NODES, 128, 0, stream>>>(
            feat, ebuf, indptr, eids, src, h_cur, 512, gat_b + l * DIM, bt);
        // BN1 (in-place on bt)
        hipMemsetAsync(stats, 0, 2 * DIM * 4, stream);
        bn_stats_kernel<<<(N_NODES + 127) / 128, 128, 0, stream>>>(bt, DIM, N_NODES, stats);
        bn_apply_kernel<<<(N_NODES * DIM + 255) / 256, 256, 0, stream>>>(
            bt, DIM, bt, DIM, bn1_g + l * DIM, bn1_b + l * DIM, stats, N_NODES);
        // FFN: y1 = relu(bt @ W1 + b1); bt = y1 @ W2 + b2 + bt
        launch_gemm(bt, DIM, ff_W1 + (size_t)l * DIM * FF_DIM, FF_DIM,
                    ff_b1 + l * FF_DIM, nullptr, 0, y1, FF_DIM,
                    N_NODES, FF_DIM, DIM, 1);
        launch_gemm(y1, FF_DIM, ff_W2 + (size_t)l * FF_DIM * DIM, DIM,
                    ff_b2 + l * DIM, bt, DIM, bt, DIM,
                    N_NODES, DIM, FF_DIM, 0);
        // BN2 -> xs[:, (l+1)*128 ...]
        hipMemsetAsync(stats, 0, 2 * DIM * 4, stream);
        bn_stats_kernel<<<(N_NODES + 127) / 128, 128, 0, stream>>>(bt, DIM, N_NODES, stats);
        bn_apply_kernel<<<(N_NODES * DIM + 255) / 256, 256, 0, stream>>>(
            bt, DIM, xs + (size_t)(l + 1) * DIM, 512,
            bn2_g + l * DIM, bn2_b + l * DIM, stats, N_NODES);
    }

    // ---- decision head: z = xs @ dec_W1 (reuse feat buffer)
    launch_gemm(xs, 512, dec_W1, DIM, nullptr, nullptr, 0, feat, DIM,
                N_NODES, DIM, 4 * DIM, 0);
    hipMemsetAsync(stats, 0, 2 * DIM * 4, stream);
    bn_stats_kernel<<<(N_NODES + 127) / 128, 128, 0, stream>>>(feat, DIM, N_NODES, stats);
    decide_kernel<<<(N_NODES + 3) / 4, 256, 0, stream>>>(
        feat, stats, dec_bn_g, dec_bn_b, dec_W2, outp, N_NODES);
}

// Round 2
// 1579.250 us; speedup vs baseline: 1.2081x; 1.2081x over previous
//
#include <hip/hip_runtime.h>
#include <math.h>

#define N_NODES 40000
#define N_EDGES 640000
#define DIM     128
#define HEADS   8
#define DHEAD   16
#define LAYERS  3
#define IN_DIM  64
#define FF_DIM  218
#define BN_EPS  1e-5f
#define NEG_SLOPE 0.2f

typedef __attribute__((ext_vector_type(8))) short  bhalf8;
typedef __attribute__((ext_vector_type(4))) float  floatx4;
typedef __attribute__((ext_vector_type(4))) int    intx4;

// fp32 -> bf16 (RNE), two packed into one dword (lo = even k, hi = odd k)
__device__ __forceinline__ unsigned bfpack2(float a, float b) {
    unsigned ua = __float_as_uint(a);
    ua = ua + 0x7FFFu + ((ua >> 16) & 1u);
    unsigned ub = __float_as_uint(b);
    ub = ub + 0x7FFFu + ((ub >> 16) & 1u);
    return (ua >> 16) | (ub & 0xFFFF0000u);
}

// ---------------------------------------------------------------- CSR build
__global__ void hist_kernel(const int* __restrict__ dst, int* __restrict__ counts) {
    int e = blockIdx.x * blockDim.x + threadIdx.x;
    if (e < N_EDGES) atomicAdd(&counts[dst[e]], 1);
}

__global__ void scan_kernel(const int* __restrict__ counts, int* __restrict__ indptr, int n) {
    __shared__ int temp[1024];
    __shared__ int carry;
    int tid = threadIdx.x;
    if (tid == 0) carry = 0;
    __syncthreads();
    for (int base = 0; base < n; base += 1024) {
        int v = (base + tid < n) ? counts[base + tid] : 0;
        temp[tid] = v;
        __syncthreads();
        for (int offs = 1; offs < 1024; offs <<= 1) {
            int t = (tid >= offs) ? temp[tid - offs] : 0;
            __syncthreads();
            temp[tid] += t;
            __syncthreads();
        }
        int incl = temp[tid];
        if (base + tid < n) indptr[base + tid] = carry + incl - v;
        __syncthreads();
        if (tid == 0) carry += temp[1023];
        __syncthreads();
    }
    if (tid == 0) indptr[n] = carry;
}

__global__ void scatter_kernel(const int* __restrict__ dst, int* __restrict__ cursor,
                               int* __restrict__ eids) {
    int e = blockIdx.x * blockDim.x + threadIdx.x;
    if (e < N_EDGES) {
        int pos = atomicAdd(&cursor[dst[e]], 1);
        eids[pos] = e;
    }
}

// ---------------------------------------------------------------- bf16 MFMA GEMM
// C[M,N] = A[M,K] @ B[K,N] (+bias) (+res) (relu?)   fp32 in/out, bf16 MFMA compute.
// Tile: 128x128, BK=32. 4 waves in 2x2; wave computes 64x64 = 4x4 mfma tiles.
// LDS layout: row-major per output-dim row, k packed 2 bf16/dword, row stride 20 dwords.
#define GBM 128
#define GBN 128
#define GBK 32
#define LDS_STRIDE 20

__global__ __launch_bounds__(256) void gemm_mfma_kernel(
    const float* __restrict__ A, int lda,
    const float* __restrict__ B, int ldb,
    const float* __restrict__ bias,
    const float* __restrict__ res, int ldres,
    float* __restrict__ C, int ldc,
    int M, int N, int K, int relu)
{
    __shared__ unsigned As[GBM * LDS_STRIDE];
    __shared__ unsigned Bs[GBN * LDS_STRIDE];

    int tid  = threadIdx.x;
    int wave = tid >> 6, lane = tid & 63;
    int q    = lane >> 4, tl = lane & 15;
    int rw   = (wave >> 1) * 64;       // wave row offset in tile
    int cw   = (wave & 1) * 64;        // wave col offset in tile
    int row0 = blockIdx.y * GBM;
    int col0 = blockIdx.x * GBN;

    floatx4 acc[4][4] = {};

    // staging assignments
    int sa_m  = tid >> 1;              // 0..127 (A row)
    int sa_k  = (tid & 1) * 16;        // 0 / 16 (A k half)
    int sb_n  = tid & 127;             // 0..127 (B col)
    int sb_kh = (tid >> 7) * 16;       // 0 / 16 (B k half)

    for (int k0 = 0; k0 < K; k0 += GBK) {
        // ---- stage A: 128 rows x 32 k
        {
            int gm = row0 + sa_m;
            unsigned pk[8];
            if (gm < M && (k0 + sa_k + 15) < K) {
                const float* ap = A + (size_t)gm * lda + (k0 + sa_k);
                #pragma unroll
                for (int d = 0; d < 8; d++)
                    pk[d] = bfpack2(ap[2 * d], ap[2 * d + 1]);
            } else {
                #pragma unroll
                for (int d = 0; d < 8; d++) {
                    int kk0 = k0 + sa_k + 2 * d;
                    float f0 = (gm < M && kk0     < K) ? A[(size_t)gm * lda + kk0]     : 0.f;
                    float f1 = (gm < M && kk0 + 1 < K) ? A[(size_t)gm * lda + kk0 + 1] : 0.f;
                    pk[d] = bfpack2(f0, f1);
                }
            }
            unsigned* dp = &As[sa_m * LDS_STRIDE + (sa_k >> 1)];
            *(intx4*)dp       = intx4{(int)pk[0], (int)pk[1], (int)pk[2], (int)pk[3]};
            *(intx4*)(dp + 4) = intx4{(int)pk[4], (int)pk[5], (int)pk[6], (int)pk[7]};
        }
        // ---- stage B: 32 k x 128 n (transposed into [n][k] packed)
        {
            int gn = col0 + sb_n;
            bool nok = gn < N;
            unsigned pk[8];
            #pragma unroll
            for (int d = 0; d < 8; d++) {
                int kk0 = k0 + sb_kh + 2 * d;
                float f0 = (nok && kk0     < K) ? B[(size_t)kk0 * ldb + gn]       : 0.f;
                float f1 = (nok && kk0 + 1 < K) ? B[(size_t)(kk0 + 1) * ldb + gn] : 0.f;
                pk[d] = bfpack2(f0, f1);
            }
            unsigned* dp = &Bs[sb_n * LDS_STRIDE + (sb_kh >> 1)];
            *(intx4*)dp       = intx4{(int)pk[0], (int)pk[1], (int)pk[2], (int)pk[3]};
            *(intx4*)(dp + 4) = intx4{(int)pk[4], (int)pk[5], (int)pk[6], (int)pk[7]};
        }
        __syncthreads();

        // ---- compute: 16 mfma per wave
        bhalf8 af[4], bf[4];
        #pragma unroll
        for (int i = 0; i < 4; i++) {
            int r = rw + i * 16 + tl;
            af[i] = *(const bhalf8*)&As[r * LDS_STRIDE + q * 4];
        }
        #pragma unroll
        for (int j = 0; j < 4; j++) {
            int c = cw + j * 16 + tl;
            bf[j] = *(const bhalf8*)&Bs[c * LDS_STRIDE + q * 4];
        }
        #pragma unroll
        for (int i = 0; i < 4; i++)
            #pragma unroll
            for (int j = 0; j < 4; j++)
                acc[i][j] = __builtin_amdgcn_mfma_f32_16x16x32_bf16(
                    af[i], bf[j], acc[i][j], 0, 0, 0);
        __syncthreads();
    }

    // ---- epilogue: C/D layout col=lane&15, row=quad*4+reg
    #pragma unroll
    for (int j = 0; j < 4; j++) {
        int c = col0 + cw + j * 16 + tl;
        if (c >= N) continue;
        float bv = bias ? bias[c] : 0.f;
        #pragma unroll
        for (int i = 0; i < 4; i++) {
            #pragma unroll
            for (int reg = 0; reg < 4; reg++) {
                int r = row0 + rw + i * 16 + q * 4 + reg;
                if (r >= M) continue;
                float v = acc[i][j][reg] + bv;
                if (res)  v += res[(size_t)r * ldres + c];
                if (relu) v = fmaxf(v, 0.f);
                C[(size_t)r * ldc + c] = v;
            }
        }
    }
}

// ---------------------------------------------------------------- GAT pieces
__global__ void eler_kernel(const float* __restrict__ feat,
                            const float* __restrict__ al, const float* __restrict__ ar,
                            float* __restrict__ el, float* __restrict__ er) {
    int i = blockIdx.x * blockDim.x + threadIdx.x;
    if (i >= N_NODES * HEADS) return;
    int n = i >> 3, h = i & 7;
    const float* f = feat + (size_t)n * DIM + h * DHEAD;
    float sl = 0.f, sr = 0.f;
    #pragma unroll
    for (int d = 0; d < DHEAD; d++) {
        float fv = f[d];
        sl = fmaf(fv, al[h * DHEAD + d], sl);
        sr = fmaf(fv, ar[h * DHEAD + d], sr);
    }
    el[i] = sl;
    er[i] = sr;
}

__global__ void edge_e_kernel(const int* __restrict__ src, const int* __restrict__ dst,
                              const float* __restrict__ el, const float* __restrict__ er,
                              float* __restrict__ ebuf) {
    int i = blockIdx.x * blockDim.x + threadIdx.x;
    if (i >= N_EDGES * HEADS) return;
    int e = i >> 3, h = i & 7;
    float v = el[src[e] * HEADS + h] + er[dst[e] * HEADS + h];
    ebuf[i] = v > 0.f ? v : NEG_SLOPE * v;
}

__global__ __launch_bounds__(128) void gat_aggregate_kernel(
    const float* __restrict__ feat, const float* __restrict__ ebuf,
    const int* __restrict__ indptr, const int* __restrict__ eids,
    const int* __restrict__ src,
    const float* __restrict__ h_in, int ldh,
    const float* __restrict__ bias,
    float* __restrict__ outp)
{
    int n = blockIdx.x;
    int t = threadIdx.x;
    __shared__ float m_s[HEADS], inv_s[HEADS];
    int beg = indptr[n], end = indptr[n + 1];
    if (t < HEADS) {
        float m = -INFINITY;
        for (int i = beg; i < end; i++) {
            float ev = ebuf[(size_t)eids[i] * HEADS + t];
            m = fmaxf(m, ev);
        }
        float s = 0.f;
        for (int i = beg; i < end; i++)
            s += expf(ebuf[(size_t)eids[i] * HEADS + t] - m);
        m_s[t] = m;
        inv_s[t] = (s > 0.f) ? 1.f / s : 0.f;
    }
    __syncthreads();
    int h = t >> 4;
    float m = m_s[h], inv = inv_s[h];
    float acc = 0.f;
    for (int i = beg; i < end; i++) {
        int eid = eids[i];
        int sn = src[eid];
        float a = expf(ebuf[(size_t)eid * HEADS + h] - m) * inv;
        acc = fmaf(a, feat[(size_t)sn * DIM + t], acc);
    }
    outp[(size_t)n * DIM + t] = h_in[(size_t)n * ldh + t] + acc + bias[t];
}

// ---------------------------------------------------------------- BatchNorm
__global__ __launch_bounds__(128) void bn_stats_kernel(const float* __restrict__ x, int ldx,
                                                       int M, float* __restrict__ stats) {
    int c = threadIdx.x;
    int r0 = blockIdx.x * 128;
    int r1 = min(r0 + 128, M);
    float s = 0.f, sq = 0.f;
    for (int r = r0; r < r1; r++) {
        float v = x[(size_t)r * ldx + c];
        s += v;
        sq = fmaf(v, v, sq);
    }
    atomicAdd(&stats[c], s);
    atomicAdd(&stats[DIM + c], sq);
}

__global__ void bn_apply_kernel(const float* __restrict__ x, int ldin,
                                float* __restrict__ y, int ldout,
                                const float* __restrict__ g, const float* __restrict__ b,
                                const float* __restrict__ stats, int M) {
    int i = blockIdx.x * blockDim.x + threadIdx.x;
    if (i >= M * DIM) return;
    int r = i >> 7, c = i & 127;
    float mu  = stats[c] * (1.f / N_NODES);
    float var = stats[DIM + c] * (1.f / N_NODES) - mu * mu;
    float v = x[(size_t)r * ldin + c];
    y[(size_t)r * ldout + c] = fmaf(g[c] * rsqrtf(var + BN_EPS), v - mu, b[c]);
}

// ---------------------------------------------------------------- decision head
__global__ __launch_bounds__(256) void decide_kernel(
    const float* __restrict__ z, const float* __restrict__ stats,
    const float* __restrict__ g, const float* __restrict__ b,
    const float* __restrict__ W2, float* __restrict__ outp, int M)
{
    int wid = threadIdx.x >> 6, lane = threadIdx.x & 63;
    int n = blockIdx.x * 4 + wid;
    if (n >= M) return;
    float acc = 0.f;
    for (int c = lane; c < DIM; c += 64) {
        float mu  = stats[c] * (1.f / N_NODES);
        float var = stats[DIM + c] * (1.f / N_NODES) - mu * mu;
        float v = fmaf(g[c] * rsqrtf(var + BN_EPS), z[(size_t)n * DIM + c] - mu, b[c]);
        v = fmaxf(v, 0.f);
        acc = fmaf(v, W2[c], acc);
    }
    #pragma unroll
    for (int offs = 32; offs > 0; offs >>= 1)
        acc += __shfl_down(acc, offs);
    if (lane == 0) outp[n] = acc;
}

// ---------------------------------------------------------------- launch
extern "C" void kernel_launch(void* const* d_in, const int* in_sizes, int n_in,
                              void* d_out, int out_size, void* d_ws, size_t ws_size,
                              hipStream_t stream)
{
    const float* x      = (const float*)d_in[0];
    const int*   src    = (const int*)  d_in[1];
    const int*   dst    = (const int*)  d_in[2];
    const float* W_emb  = (const float*)d_in[3];
    const float* b_emb  = (const float*)d_in[4];
    const float* gat_W  = (const float*)d_in[5];
    const float* attn_l = (const float*)d_in[6];
    const float* attn_r = (const float*)d_in[7];
    const float* gat_b  = (const float*)d_in[8];
    const float* bn1_g  = (const float*)d_in[9];
    const float* bn1_b  = (const float*)d_in[10];
    const float* ff_W1  = (const float*)d_in[11];
    const float* ff_b1  = (const float*)d_in[12];
    const float* ff_W2  = (const float*)d_in[13];
    const float* ff_b2  = (const float*)d_in[14];
    const float* bn2_g  = (const float*)d_in[15];
    const float* bn2_b  = (const float*)d_in[16];
    const float* dec_W1 = (const float*)d_in[17];
    const float* dec_bn_g = (const float*)d_in[18];
    const float* dec_bn_b = (const float*)d_in[19];
    const float* dec_W2 = (const float*)d_in[20];
    float* outp = (float*)d_out;

    char* ws = (char*)d_ws;
    size_t off = 0;
    auto alloc = [&](size_t bytes) -> void* {
        void* p = ws + off;
        off += (bytes + 255) & ~(size_t)255;
        return p;
    };
    float* xs    = (float*)alloc((size_t)N_NODES * 512 * 4);
    float* feat  = (float*)alloc((size_t)N_NODES * DIM * 4);
    float* el    = (float*)alloc((size_t)N_NODES * HEADS * 4);
    float* er    = (float*)alloc((size_t)N_NODES * HEADS * 4);
    float* ebuf  = (float*)alloc((size_t)N_EDGES * HEADS * 4);
    float* y1    = (float*)alloc((size_t)N_NODES * FF_DIM * 4);
    float* bt    = (float*)alloc((size_t)N_NODES * DIM * 4);
    float* stats = (float*)alloc(2 * DIM * 4);
    int*   counts= (int*)  alloc((size_t)N_NODES * 4);
    int*   indptr= (int*)  alloc((size_t)(N_NODES + 1) * 4);
    int*   cursor= (int*)  alloc((size_t)N_NODES * 4);
    int*   eids  = (int*)  alloc((size_t)N_EDGES * 4);
    (void)ws_size; (void)in_sizes; (void)n_in; (void)out_size;

    auto launch_gemm = [&](const float* A, int lda, const float* B, int ldb,
                           const float* bias, const float* res, int ldres,
                           float* C, int ldc, int M, int N, int K, int relu) {
        dim3 grid((N + GBN - 1) / GBN, (M + GBM - 1) / GBM);
        gemm_mfma_kernel<<<grid, 256, 0, stream>>>(A, lda, B, ldb, bias, res, ldres,
                                                   C, ldc, M, N, K, relu);
    };

    // ---- CSR build
    hipMemsetAsync(counts, 0, N_NODES * 4, stream);
    hist_kernel<<<(N_EDGES + 255) / 256, 256, 0, stream>>>(dst, counts);
    scan_kernel<<<1, 1024, 0, stream>>>(counts, indptr, N_NODES);
    hipMemcpyAsync(cursor, indptr, N_NODES * 4, hipMemcpyDeviceToDevice, stream);
    scatter_kernel<<<(N_EDGES + 255) / 256, 256, 0, stream>>>(dst, cursor, eids);

    // ---- embed
    launch_gemm(x, IN_DIM, W_emb, DIM, b_emb, nullptr, 0, xs, 512,
                N_NODES, DIM, IN_DIM, 0);

    for (int l = 0; l < LAYERS; l++) {
        const float* h_cur = xs + (size_t)l * DIM;
        launch_gemm(h_cur, 512, gat_W + (size_t)l * DIM * DIM, DIM,
                    nullptr, nullptr, 0, feat, DIM, N_NODES, DIM, DIM, 0);
        eler_kernel<<<(N_NODES * HEADS + 255) / 256, 256, 0, stream>>>(
            feat, attn_l + l * DIM, attn_r + l * DIM, el, er);
        edge_e_kernel<<<(N_EDGES * HEADS + 255) / 256, 256, 0, stream>>>(
            src, dst, el, er, ebuf);
        gat_aggregate_kernel<<<N_NODES, 128, 0, stream>>>(
            feat, ebuf, indptr, eids, src, h_cur, 512, gat_b + l * DIM, bt);
        hipMemsetAsync(stats, 0, 2 * DIM * 4, stream);
        bn_stats_kernel<<<(N_NODES + 127) / 128, 128, 0, stream>>>(bt, DIM, N_NODES, stats);
        bn_apply_kernel<<<(N_NODES * DIM + 255) / 256, 256, 0, stream>>>(
            bt, DIM, bt, DIM, bn1_g + l * DIM, bn1_b + l * DIM, stats, N_NODES);
        launch_gemm(bt, DIM, ff_W1 + (size_t)l * DIM * FF_DIM, FF_DIM,
                    ff_b1 + l * FF_DIM, nullptr, 0, y1, FF_DIM,
                    N_NODES, FF_DIM, DIM, 1);
        launch_gemm(y1, FF_DIM, ff_W2 + (size_t)l * FF_DIM * DIM, DIM,
                    ff_b2 + l * DIM, bt, DIM, bt, DIM,
                    N_NODES, DIM, FF_DIM, 0);
        hipMemsetAsync(stats, 0, 2 * DIM * 4, stream);
        bn_stats_kernel<<<(N_NODES + 127) / 128, 128, 0, stream>>>(bt, DIM, N_NODES, stats);
        bn_apply_kernel<<<(N_NODES * DIM + 255) / 256, 256, 0, stream>>>(
            bt, DIM, xs + (size_t)(l + 1) * DIM, 512,
            bn2_g + l * DIM, bn2_b + l * DIM, stats, N_NODES);
    }

    // ---- decision head
    launch_gemm(xs, 512, dec_W1, DIM, nullptr, nullptr, 0, feat, DIM,
                N_NODES, DIM, 4 * DIM, 0);
    hipMemsetAsync(stats, 0, 2 * DIM * 4, stream);
    bn_stats_kernel<<<(N_NODES + 127) / 128, 128, 0, stream>>>(feat, DIM, N_NODES, stats);
    decide_kernel<<<(N_NODES + 3) / 4, 256, 0, stream>>>(
        feat, stats, dec_bn_g, dec_bn_b, dec_W2, outp, N_NODES);
}

// Round 3
// 1299.594 us; speedup vs baseline: 1.4681x; 1.2152x over previous
//
#include <hip/hip_runtime.h>
#include <math.h>

#define N_NODES 40000
#define N_EDGES 640000
#define DIM     128
#define HEADS   8
#define DHEAD   16
#define LAYERS  3
#define IN_DIM  64
#define FF_DIM  218
#define BN_EPS  1e-5f
#define NEG_SLOPE 0.2f

typedef __attribute__((ext_vector_type(8))) short  bhalf8;
typedef __attribute__((ext_vector_type(4))) float  floatx4;
typedef __attribute__((ext_vector_type(4))) int    intx4;

// fp32 -> bf16 (RNE), two packed into one dword (lo = even k, hi = odd k)
__device__ __forceinline__ unsigned bfpack2(float a, float b) {
    unsigned ua = __float_as_uint(a);
    ua = ua + 0x7FFFu + ((ua >> 16) & 1u);
    unsigned ub = __float_as_uint(b);
    ub = ub + 0x7FFFu + ((ub >> 16) & 1u);
    return (ua >> 16) | (ub & 0xFFFF0000u);
}

// ---------------------------------------------------------------- CSR build
__global__ void hist_kernel(const int* __restrict__ dst, int* __restrict__ counts) {
    int e = blockIdx.x * blockDim.x + threadIdx.x;
    if (e < N_EDGES) atomicAdd(&counts[dst[e]], 1);
}

__global__ void scan_kernel(const int* __restrict__ counts, int* __restrict__ indptr, int n) {
    __shared__ int temp[1024];
    __shared__ int carry;
    int tid = threadIdx.x;
    if (tid == 0) carry = 0;
    __syncthreads();
    for (int base = 0; base < n; base += 1024) {
        int v = (base + tid < n) ? counts[base + tid] : 0;
        temp[tid] = v;
        __syncthreads();
        for (int offs = 1; offs < 1024; offs <<= 1) {
            int t = (tid >= offs) ? temp[tid - offs] : 0;
            __syncthreads();
            temp[tid] += t;
            __syncthreads();
        }
        int incl = temp[tid];
        if (base + tid < n) indptr[base + tid] = carry + incl - v;
        __syncthreads();
        if (tid == 0) carry += temp[1023];
        __syncthreads();
    }
    if (tid == 0) indptr[n] = carry;
}

__global__ void scatter_kernel(const int* __restrict__ dst, int* __restrict__ cursor,
                               int* __restrict__ eids) {
    int e = blockIdx.x * blockDim.x + threadIdx.x;
    if (e < N_EDGES) {
        int pos = atomicAdd(&cursor[dst[e]], 1);
        eids[pos] = e;
    }
}

// ---------------------------------------------------------------- bf16 MFMA GEMM
#define GBM 128
#define GBN 128
#define GBK 32
#define LDS_STRIDE 20

__global__ __launch_bounds__(256) void gemm_mfma_kernel(
    const float* __restrict__ A, int lda,
    const float* __restrict__ B, int ldb,
    const float* __restrict__ bias,
    const float* __restrict__ res, int ldres,
    float* __restrict__ C, int ldc,
    int M, int N, int K, int relu)
{
    __shared__ unsigned As[GBM * LDS_STRIDE];
    __shared__ unsigned Bs[GBN * LDS_STRIDE];

    int tid  = threadIdx.x;
    int wave = tid >> 6, lane = tid & 63;
    int q    = lane >> 4, tl = lane & 15;
    int rw   = (wave >> 1) * 64;
    int cw   = (wave & 1) * 64;
    int row0 = blockIdx.y * GBM;
    int col0 = blockIdx.x * GBN;

    floatx4 acc[4][4] = {};

    int sa_m  = tid >> 1;
    int sa_k  = (tid & 1) * 16;
    int sb_n  = tid & 127;
    int sb_kh = (tid >> 7) * 16;

    for (int k0 = 0; k0 < K; k0 += GBK) {
        {
            int gm = row0 + sa_m;
            unsigned pk[8];
            if (gm < M && (k0 + sa_k + 15) < K) {
                const float* ap = A + (size_t)gm * lda + (k0 + sa_k);
                #pragma unroll
                for (int d = 0; d < 8; d++)
                    pk[d] = bfpack2(ap[2 * d], ap[2 * d + 1]);
            } else {
                #pragma unroll
                for (int d = 0; d < 8; d++) {
                    int kk0 = k0 + sa_k + 2 * d;
                    float f0 = (gm < M && kk0     < K) ? A[(size_t)gm * lda + kk0]     : 0.f;
                    float f1 = (gm < M && kk0 + 1 < K) ? A[(size_t)gm * lda + kk0 + 1] : 0.f;
                    pk[d] = bfpack2(f0, f1);
                }
            }
            unsigned* dp = &As[sa_m * LDS_STRIDE + (sa_k >> 1)];
            *(intx4*)dp       = intx4{(int)pk[0], (int)pk[1], (int)pk[2], (int)pk[3]};
            *(intx4*)(dp + 4) = intx4{(int)pk[4], (int)pk[5], (int)pk[6], (int)pk[7]};
        }
        {
            int gn = col0 + sb_n;
            bool nok = gn < N;
            unsigned pk[8];
            #pragma unroll
            for (int d = 0; d < 8; d++) {
                int kk0 = k0 + sb_kh + 2 * d;
                float f0 = (nok && kk0     < K) ? B[(size_t)kk0 * ldb + gn]       : 0.f;
                float f1 = (nok && kk0 + 1 < K) ? B[(size_t)(kk0 + 1) * ldb + gn] : 0.f;
                pk[d] = bfpack2(f0, f1);
            }
            unsigned* dp = &Bs[sb_n * LDS_STRIDE + (sb_kh >> 1)];
            *(intx4*)dp       = intx4{(int)pk[0], (int)pk[1], (int)pk[2], (int)pk[3]};
            *(intx4*)(dp + 4) = intx4{(int)pk[4], (int)pk[5], (int)pk[6], (int)pk[7]};
        }
        __syncthreads();

        bhalf8 af[4], bf[4];
        #pragma unroll
        for (int i = 0; i < 4; i++) {
            int r = rw + i * 16 + tl;
            af[i] = *(const bhalf8*)&As[r * LDS_STRIDE + q * 4];
        }
        #pragma unroll
        for (int j = 0; j < 4; j++) {
            int c = cw + j * 16 + tl;
            bf[j] = *(const bhalf8*)&Bs[c * LDS_STRIDE + q * 4];
        }
        #pragma unroll
        for (int i = 0; i < 4; i++)
            #pragma unroll
            for (int j = 0; j < 4; j++)
                acc[i][j] = __builtin_amdgcn_mfma_f32_16x16x32_bf16(
                    af[i], bf[j], acc[i][j], 0, 0, 0);
        __syncthreads();
    }

    #pragma unroll
    for (int j = 0; j < 4; j++) {
        int c = col0 + cw + j * 16 + tl;
        if (c >= N) continue;
        float bv = bias ? bias[c] : 0.f;
        #pragma unroll
        for (int i = 0; i < 4; i++) {
            #pragma unroll
            for (int reg = 0; reg < 4; reg++) {
                int r = row0 + rw + i * 16 + q * 4 + reg;
                if (r >= M) continue;
                float v = acc[i][j][reg] + bv;
                if (res)  v += res[(size_t)r * ldres + c];
                if (relu) v = fmaxf(v, 0.f);
                C[(size_t)r * ldc + c] = v;
            }
        }
    }
}

// ---------------------------------------------------------------- GAT pieces
__global__ void eler_kernel(const float* __restrict__ feat,
                            const float* __restrict__ al, const float* __restrict__ ar,
                            float* __restrict__ el, float* __restrict__ er) {
    int i = blockIdx.x * blockDim.x + threadIdx.x;
    if (i >= N_NODES * HEADS) return;
    int n = i >> 3, h = i & 7;
    const float* f = feat + (size_t)n * DIM + h * DHEAD;
    float sl = 0.f, sr = 0.f;
    #pragma unroll
    for (int d = 0; d < DHEAD; d++) {
        float fv = f[d];
        sl = fmaf(fv, al[h * DHEAD + d], sl);
        sr = fmaf(fv, ar[h * DHEAD + d], sr);
    }
    el[i] = sl;
    er[i] = sr;
}

// ebuf[e,h] = exp(leaky_relu(el[src]+er[dst]))  -- no max subtraction (exact cancellation,
// values are O(1) since inputs are BN-normalized; exp overflow impossible)
__global__ void edge_exp_kernel(const int* __restrict__ src, const int* __restrict__ dst,
                                const float* __restrict__ el, const float* __restrict__ er,
                                float* __restrict__ ebuf) {
    int i = blockIdx.x * blockDim.x + threadIdx.x;
    if (i >= N_EDGES * HEADS) return;
    int e = i >> 3, h = i & 7;
    float v = el[src[e] * HEADS + h] + er[dst[e] * HEADS + h];
    v = v > 0.f ? v : NEG_SLOPE * v;
    ebuf[i] = expf(v);
}

// per-dst-node: den per head (32-edge-parallel), then aggregate with 8 gather chains in flight
__global__ __launch_bounds__(256) void gat_aggregate_kernel(
    const float* __restrict__ feat, const float* __restrict__ ebuf,
    const int* __restrict__ indptr, const int* __restrict__ eids,
    const int* __restrict__ src,
    const float* __restrict__ h_in, int ldh,
    const float* __restrict__ bias,
    float* __restrict__ outp)
{
    int n = blockIdx.x;
    int t = threadIdx.x;
    __shared__ float inv_s[HEADS];
    __shared__ float red[256];
    int beg = indptr[n], end = indptr[n + 1];

    // phase 1: denominator per head, 32 edges x 8 heads parallel
    {
        int j = t >> 3, h = t & 7;
        float s = 0.f;
        for (int i = beg + j; i < end; i += 32)
            s += ebuf[(size_t)eids[i] * HEADS + h];
        red[t] = s;
    }
    __syncthreads();
    if (t < HEADS) {
        float s = 0.f;
        #pragma unroll
        for (int j = 0; j < 32; j++) s += red[j * 8 + t];
        inv_s[t] = (s > 0.f) ? 1.f / s : 0.f;
    }
    __syncthreads();

    // phase 2: aggregate, 2 groups x 4-way unroll = 8 edges in flight
    int p = t >> 7;          // 0/1 edge group
    int d = t & 127;         // feature dim
    int hh = d >> 4;         // head of this dim
    float inv = inv_s[hh];
    float acc = 0.f;
    int i = beg + p;
    for (; i + 6 < end; i += 8) {
        int e0 = eids[i], e1 = eids[i + 2], e2 = eids[i + 4], e3 = eids[i + 6];
        int s0 = src[e0], s1 = src[e1], s2 = src[e2], s3 = src[e3];
        float a0 = ebuf[(size_t)e0 * HEADS + hh];
        float a1 = ebuf[(size_t)e1 * HEADS + hh];
        float a2 = ebuf[(size_t)e2 * HEADS + hh];
        float a3 = ebuf[(size_t)e3 * HEADS + hh];
        float f0 = feat[(size_t)s0 * DIM + d];
        float f1 = feat[(size_t)s1 * DIM + d];
        float f2 = feat[(size_t)s2 * DIM + d];
        float f3 = feat[(size_t)s3 * DIM + d];
        acc = fmaf(a0, f0, acc);
        acc = fmaf(a1, f1, acc);
        acc = fmaf(a2, f2, acc);
        acc = fmaf(a3, f3, acc);
    }
    for (; i < end; i += 2) {
        int e0 = eids[i];
        int s0 = src[e0];
        acc = fmaf(ebuf[(size_t)e0 * HEADS + hh], feat[(size_t)s0 * DIM + d], acc);
    }
    acc *= inv;
    __syncthreads();
    red[t] = acc;
    __syncthreads();
    if (t < 128) {
        float v = red[d] + red[128 + d];
        outp[(size_t)n * DIM + d] = h_in[(size_t)n * ldh + d] + v + bias[d];
    }
}

// ---------------------------------------------------------------- BatchNorm
__global__ __launch_bounds__(128) void bn_stats_kernel(const float* __restrict__ x, int ldx,
                                                       int M, float* __restrict__ stats) {
    int c = threadIdx.x;
    int r0 = blockIdx.x * 128;
    int r1 = min(r0 + 128, M);
    float s = 0.f, sq = 0.f;
    for (int r = r0; r < r1; r++) {
        float v = x[(size_t)r * ldx + c];
        s += v;
        sq = fmaf(v, v, sq);
    }
    atomicAdd(&stats[c], s);
    atomicAdd(&stats[DIM + c], sq);
}

__global__ void bn_apply_kernel(const float* __restrict__ x, int ldin,
                                float* __restrict__ y, int ldout,
                                const float* __restrict__ g, const float* __restrict__ b,
                                const float* __restrict__ stats, int M) {
    int i = blockIdx.x * blockDim.x + threadIdx.x;
    if (i >= M * DIM) return;
    int r = i >> 7, c = i & 127;
    float mu  = stats[c] * (1.f / N_NODES);
    float var = stats[DIM + c] * (1.f / N_NODES) - mu * mu;
    float v = x[(size_t)r * ldin + c];
    y[(size_t)r * ldout + c] = fmaf(g[c] * rsqrtf(var + BN_EPS), v - mu, b[c]);
}

// ---------------------------------------------------------------- decision head
__global__ __launch_bounds__(256) void decide_kernel(
    const float* __restrict__ z, const float* __restrict__ stats,
    const float* __restrict__ g, const float* __restrict__ b,
    const float* __restrict__ W2, float* __restrict__ outp, int M)
{
    int wid = threadIdx.x >> 6, lane = threadIdx.x & 63;
    int n = blockIdx.x * 4 + wid;
    if (n >= M) return;
    float acc = 0.f;
    for (int c = lane; c < DIM; c += 64) {
        float mu  = stats[c] * (1.f / N_NODES);
        float var = stats[DIM + c] * (1.f / N_NODES) - mu * mu;
        float v = fmaf(g[c] * rsqrtf(var + BN_EPS), z[(size_t)n * DIM + c] - mu, b[c]);
        v = fmaxf(v, 0.f);
        acc = fmaf(v, W2[c], acc);
    }
    #pragma unroll
    for (int offs = 32; offs > 0; offs >>= 1)
        acc += __shfl_down(acc, offs);
    if (lane == 0) outp[n] = acc;
}

// ---------------------------------------------------------------- launch
extern "C" void kernel_launch(void* const* d_in, const int* in_sizes, int n_in,
                              void* d_out, int out_size, void* d_ws, size_t ws_size,
                              hipStream_t stream)
{
    const float* x      = (const float*)d_in[0];
    const int*   src    = (const int*)  d_in[1];
    const int*   dst    = (const int*)  d_in[2];
    const float* W_emb  = (const float*)d_in[3];
    const float* b_emb  = (const float*)d_in[4];
    const float* gat_W  = (const float*)d_in[5];
    const float* attn_l = (const float*)d_in[6];
    const float* attn_r = (const float*)d_in[7];
    const float* gat_b  = (const float*)d_in[8];
    const float* bn1_g  = (const float*)d_in[9];
    const float* bn1_b  = (const float*)d_in[10];
    const float* ff_W1  = (const float*)d_in[11];
    const float* ff_b1  = (const float*)d_in[12];
    const float* ff_W2  = (const float*)d_in[13];
    const float* ff_b2  = (const float*)d_in[14];
    const float* bn2_g  = (const float*)d_in[15];
    const float* bn2_b  = (const float*)d_in[16];
    const float* dec_W1 = (const float*)d_in[17];
    const float* dec_bn_g = (const float*)d_in[18];
    const float* dec_bn_b = (const float*)d_in[19];
    const float* dec_W2 = (const float*)d_in[20];
    float* outp = (float*)d_out;

    char* ws = (char*)d_ws;
    size_t off = 0;
    auto alloc = [&](size_t bytes) -> void* {
        void* p = ws + off;
        off += (bytes + 255) & ~(size_t)255;
        return p;
    };
    float* xs    = (float*)alloc((size_t)N_NODES * 512 * 4);
    float* feat  = (float*)alloc((size_t)N_NODES * DIM * 4);
    float* el    = (float*)alloc((size_t)N_NODES * HEADS * 4);
    float* er    = (float*)alloc((size_t)N_NODES * HEADS * 4);
    float* ebuf  = (float*)alloc((size_t)N_EDGES * HEADS * 4);
    float* y1    = (float*)alloc((size_t)N_NODES * FF_DIM * 4);
    float* bt    = (float*)alloc((size_t)N_NODES * DIM * 4);
    float* stats = (float*)alloc(2 * DIM * 4);
    int*   counts= (int*)  alloc((size_t)N_NODES * 4);
    int*   indptr= (int*)  alloc((size_t)(N_NODES + 1) * 4);
    int*   cursor= (int*)  alloc((size_t)N_NODES * 4);
    int*   eids  = (int*)  alloc((size_t)N_EDGES * 4);
    (void)ws_size; (void)in_sizes; (void)n_in; (void)out_size;

    auto launch_gemm = [&](const float* A, int lda, const float* B, int ldb,
                           const float* bias, const float* res, int ldres,
                           float* C, int ldc, int M, int N, int K, int relu) {
        dim3 grid((N + GBN - 1) / GBN, (M + GBM - 1) / GBM);
        gemm_mfma_kernel<<<grid, 256, 0, stream>>>(A, lda, B, ldb, bias, res, ldres,
                                                   C, ldc, M, N, K, relu);
    };

    // ---- CSR build
    hipMemsetAsync(counts, 0, N_NODES * 4, stream);
    hist_kernel<<<(N_EDGES + 255) / 256, 256, 0, stream>>>(dst, counts);
    scan_kernel<<<1, 1024, 0, stream>>>(counts, indptr, N_NODES);
    hipMemcpyAsync(cursor, indptr, N_NODES * 4, hipMemcpyDeviceToDevice, stream);
    scatter_kernel<<<(N_EDGES + 255) / 256, 256, 0, stream>>>(dst, cursor, eids);

    // ---- embed
    launch_gemm(x, IN_DIM, W_emb, DIM, b_emb, nullptr, 0, xs, 512,
                N_NODES, DIM, IN_DIM, 0);

    for (int l = 0; l < LAYERS; l++) {
        const float* h_cur = xs + (size_t)l * DIM;
        launch_gemm(h_cur, 512, gat_W + (size_t)l * DIM * DIM, DIM,
                    nullptr, nullptr, 0, feat, DIM, N_NODES, DIM, DIM, 0);
        eler_kernel<<<(N_NODES * HEADS + 255) / 256, 256, 0, stream>>>(
            feat, attn_l + l * DIM, attn_r + l * DIM, el, er);
        edge_exp_kernel<<<(N_EDGES * HEADS + 255) / 256, 256, 0, stream>>>(
            src, dst, el, er, ebuf);
        gat_aggregate_kernel<<<N_NODES, 256, 0, stream>>>(
            feat, ebuf, indptr, eids, src, h_cur, 512, gat_b + l * DIM, bt);
        hipMemsetAsync(stats, 0, 2 * DIM * 4, stream);
        bn_stats_kernel<<<(N_NODES + 127) / 128, 128, 0, stream>>>(bt, DIM, N_NODES, stats);
        bn_apply_kernel<<<(N_NODES * DIM + 255) / 256, 256, 0, stream>>>(
            bt, DIM, bt, DIM, bn1_g + l * DIM, bn1_b + l * DIM, stats, N_NODES);
        launch_gemm(bt, DIM, ff_W1 + (size_t)l * DIM * FF_DIM, FF_DIM,
                    ff_b1 + l * FF_DIM, nullptr, 0, y1, FF_DIM,
                    N_NODES, FF_DIM, DIM, 1);
        launch_gemm(y1, FF_DIM, ff_W2 + (size_t)l * FF_DIM * DIM, DIM,
                    ff_b2 + l * DIM, bt, DIM, bt, DIM,
                    N_NODES, DIM, FF_DIM, 0);
        hipMemsetAsync(stats, 0, 2 * DIM * 4, stream);
        bn_stats_kernel<<<(N_NODES + 127) / 128, 128, 0, stream>>>(bt, DIM, N_NODES, stats);
        bn_apply_kernel<<<(N_NODES * DIM + 255) / 256, 256, 0, stream>>>(
            bt, DIM, xs + (size_t)(l + 1) * DIM, 512,
            bn2_g + l * DIM, bn2_b + l * DIM, stats, N_NODES);
    }

    // ---- decision head
    launch_gemm(xs, 512, dec_W1, DIM, nullptr, nullptr, 0, feat, DIM,
                N_NODES, DIM, 4 * DIM, 0);
    hipMemsetAsync(stats, 0, 2 * DIM * 4, stream);
    bn_stats_kernel<<<(N_NODES + 127) / 128, 128, 0, stream>>>(feat, DIM, N_NODES, stats);
    decide_kernel<<<(N_NODES + 3) / 4, 256, 0, stream>>>(
        feat, stats, dec_bn_g, dec_bn_b, dec_W2, outp, N_NODES);
}

// Round 4
// 1191.947 us; speedup vs baseline: 1.6007x; 1.0903x over previous
//
#include <hip/hip_runtime.h>
#include <hip/hip_bf16.h>
#include <math.h>

#define N_NODES 40000
#define N_EDGES 640000
#define DIM     128
#define HEADS   8
#define DHEAD   16
#define LAYERS  3
#define IN_DIM  64
#define FF_DIM  218
#define BN_EPS  1e-5f
#define NEG_SLOPE 0.2f

typedef __attribute__((ext_vector_type(8))) short  bhalf8;
typedef __attribute__((ext_vector_type(4))) float  floatx4;
typedef __attribute__((ext_vector_type(4))) int    intx4;

// fp32 -> bf16 (RNE), two packed into one dword (lo = even k, hi = odd k)
__device__ __forceinline__ unsigned bfpack2(float a, float b) {
    unsigned ua = __float_as_uint(a);
    ua = ua + 0x7FFFu + ((ua >> 16) & 1u);
    unsigned ub = __float_as_uint(b);
    ub = ub + 0x7FFFu + ((ub >> 16) & 1u);
    return (ua >> 16) | (ub & 0xFFFF0000u);
}
__device__ __forceinline__ unsigned short bf16of(float a) {
    unsigned ua = __float_as_uint(a);
    ua = ua + 0x7FFFu + ((ua >> 16) & 1u);
    return (unsigned short)(ua >> 16);
}
__device__ __forceinline__ float bf2f(unsigned short u) {
    unsigned v = ((unsigned)u) << 16;
    return __uint_as_float(v);
}

// ---------------------------------------------------------------- CSR build
__global__ void hist_kernel(const int* __restrict__ dst, int* __restrict__ counts) {
    int e = blockIdx.x * blockDim.x + threadIdx.x;
    if (e < N_EDGES) atomicAdd(&counts[dst[e]], 1);
}

__global__ void scan_kernel(const int* __restrict__ counts, int* __restrict__ indptr, int n) {
    __shared__ int temp[1024];
    __shared__ int carry;
    int tid = threadIdx.x;
    if (tid == 0) carry = 0;
    __syncthreads();
    for (int base = 0; base < n; base += 1024) {
        int v = (base + tid < n) ? counts[base + tid] : 0;
        temp[tid] = v;
        __syncthreads();
        for (int offs = 1; offs < 1024; offs <<= 1) {
            int t = (tid >= offs) ? temp[tid - offs] : 0;
            __syncthreads();
            temp[tid] += t;
            __syncthreads();
        }
        int incl = temp[tid];
        if (base + tid < n) indptr[base + tid] = carry + incl - v;
        __syncthreads();
        if (tid == 0) carry += temp[1023];
        __syncthreads();
    }
    if (tid == 0) indptr[n] = carry;
}

// CSR scatter: record src node per CSR slot and CSR position per edge
__global__ void scatter_kernel(const int* __restrict__ src, const int* __restrict__ dst,
                               int* __restrict__ cursor,
                               int* __restrict__ srcs_csr, int* __restrict__ epos) {
    int e = blockIdx.x * blockDim.x + threadIdx.x;
    if (e < N_EDGES) {
        int pos = atomicAdd(&cursor[dst[e]], 1);
        srcs_csr[pos] = src[e];
        epos[e] = pos;
    }
}

// ---------------------------------------------------------------- bf16 MFMA GEMM
#define GBM 128
#define GBN 128
#define GBK 32
#define LDS_STRIDE 20

__global__ __launch_bounds__(256) void gemm_mfma_kernel(
    const float* __restrict__ A, int lda,
    const float* __restrict__ B, int ldb,
    const float* __restrict__ bias,
    const float* __restrict__ res, int ldres,
    float* __restrict__ C, int ldc,
    int M, int N, int K, int relu,
    unsigned short* __restrict__ Cbf)       // if non-null, also/only store bf16
{
    __shared__ unsigned As[GBM * LDS_STRIDE];
    __shared__ unsigned Bs[GBN * LDS_STRIDE];

    int tid  = threadIdx.x;
    int wave = tid >> 6, lane = tid & 63;
    int q    = lane >> 4, tl = lane & 15;
    int rw   = (wave >> 1) * 64;
    int cw   = (wave & 1) * 64;
    int row0 = blockIdx.y * GBM;
    int col0 = blockIdx.x * GBN;

    floatx4 acc[4][4] = {};

    int sa_m  = tid >> 1;
    int sa_k  = (tid & 1) * 16;
    int sb_n  = tid & 127;
    int sb_kh = (tid >> 7) * 16;

    for (int k0 = 0; k0 < K; k0 += GBK) {
        {
            int gm = row0 + sa_m;
            unsigned pk[8];
            if (gm < M && (k0 + sa_k + 15) < K) {
                const float* ap = A + (size_t)gm * lda + (k0 + sa_k);
                #pragma unroll
                for (int d = 0; d < 8; d++)
                    pk[d] = bfpack2(ap[2 * d], ap[2 * d + 1]);
            } else {
                #pragma unroll
                for (int d = 0; d < 8; d++) {
                    int kk0 = k0 + sa_k + 2 * d;
                    float f0 = (gm < M && kk0     < K) ? A[(size_t)gm * lda + kk0]     : 0.f;
                    float f1 = (gm < M && kk0 + 1 < K) ? A[(size_t)gm * lda + kk0 + 1] : 0.f;
                    pk[d] = bfpack2(f0, f1);
                }
            }
            unsigned* dp = &As[sa_m * LDS_STRIDE + (sa_k >> 1)];
            *(intx4*)dp       = intx4{(int)pk[0], (int)pk[1], (int)pk[2], (int)pk[3]};
            *(intx4*)(dp + 4) = intx4{(int)pk[4], (int)pk[5], (int)pk[6], (int)pk[7]};
        }
        {
            int gn = col0 + sb_n;
            bool nok = gn < N;
            unsigned pk[8];
            #pragma unroll
            for (int d = 0; d < 8; d++) {
                int kk0 = k0 + sb_kh + 2 * d;
                float f0 = (nok && kk0     < K) ? B[(size_t)kk0 * ldb + gn]       : 0.f;
                float f1 = (nok && kk0 + 1 < K) ? B[(size_t)(kk0 + 1) * ldb + gn] : 0.f;
                pk[d] = bfpack2(f0, f1);
            }
            unsigned* dp = &Bs[sb_n * LDS_STRIDE + (sb_kh >> 1)];
            *(intx4*)dp       = intx4{(int)pk[0], (int)pk[1], (int)pk[2], (int)pk[3]};
            *(intx4*)(dp + 4) = intx4{(int)pk[4], (int)pk[5], (int)pk[6], (int)pk[7]};
        }
        __syncthreads();

        bhalf8 af[4], bf[4];
        #pragma unroll
        for (int i = 0; i < 4; i++) {
            int r = rw + i * 16 + tl;
            af[i] = *(const bhalf8*)&As[r * LDS_STRIDE + q * 4];
        }
        #pragma unroll
        for (int j = 0; j < 4; j++) {
            int c = cw + j * 16 + tl;
            bf[j] = *(const bhalf8*)&Bs[c * LDS_STRIDE + q * 4];
        }
        #pragma unroll
        for (int i = 0; i < 4; i++)
            #pragma unroll
            for (int j = 0; j < 4; j++)
                acc[i][j] = __builtin_amdgcn_mfma_f32_16x16x32_bf16(
                    af[i], bf[j], acc[i][j], 0, 0, 0);
        __syncthreads();
    }

    #pragma unroll
    for (int j = 0; j < 4; j++) {
        int c = col0 + cw + j * 16 + tl;
        if (c >= N) continue;
        float bv = bias ? bias[c] : 0.f;
        #pragma unroll
        for (int i = 0; i < 4; i++) {
            #pragma unroll
            for (int reg = 0; reg < 4; reg++) {
                int r = row0 + rw + i * 16 + q * 4 + reg;
                if (r >= M) continue;
                float v = acc[i][j][reg] + bv;
                if (res)  v += res[(size_t)r * ldres + c];
                if (relu) v = fmaxf(v, 0.f);
                if (Cbf) Cbf[(size_t)r * ldc + c] = bf16of(v);
                else     C  [(size_t)r * ldc + c] = v;
            }
        }
    }
}

// ---------------------------------------------------------------- GAT pieces
__global__ void eler_kernel(const unsigned short* __restrict__ feat,
                            const float* __restrict__ al, const float* __restrict__ ar,
                            float* __restrict__ el, float* __restrict__ er) {
    int i = blockIdx.x * blockDim.x + threadIdx.x;
    if (i >= N_NODES * HEADS) return;
    int n = i >> 3, h = i & 7;
    const unsigned short* f = feat + (size_t)n * DIM + h * DHEAD;
    float sl = 0.f, sr = 0.f;
    #pragma unroll
    for (int d = 0; d < DHEAD; d++) {
        float fv = bf2f(f[d]);
        sl = fmaf(fv, al[h * DHEAD + d], sl);
        sr = fmaf(fv, ar[h * DHEAD + d], sr);
    }
    el[i] = sl;
    er[i] = sr;
}

// ebuf_csr[epos[e]*8+h] = exp(leaky_relu(el[src]+er[dst]))
__global__ void edge_exp_kernel(const int* __restrict__ src, const int* __restrict__ dst,
                                const int* __restrict__ epos,
                                const float* __restrict__ el, const float* __restrict__ er,
                                float* __restrict__ ebuf_csr) {
    int i = blockIdx.x * blockDim.x + threadIdx.x;
    if (i >= N_EDGES * HEADS) return;
    int e = i >> 3, h = i & 7;
    float v = el[src[e] * HEADS + h] + er[dst[e] * HEADS + h];
    v = v > 0.f ? v : NEG_SLOPE * v;
    ebuf_csr[(size_t)epos[e] * HEADS + h] = expf(v);
}

// per-dst-node: contiguous alpha + src reads, single gather level on bf16 feat
__global__ __launch_bounds__(256) void gat_aggregate_kernel(
    const unsigned short* __restrict__ feat, const float* __restrict__ ebuf_csr,
    const int* __restrict__ indptr, const int* __restrict__ srcs_csr,
    const float* __restrict__ h_in, int ldh,
    const float* __restrict__ bias,
    float* __restrict__ outp)
{
    int n = blockIdx.x;
    int t = threadIdx.x;
    __shared__ float inv_s[HEADS];
    __shared__ float red[256];
    int beg = indptr[n], end = indptr[n + 1];

    // phase 1: denominator per head, 32 edges x 8 heads parallel (contiguous reads)
    {
        int j = t >> 3, h = t & 7;
        float s = 0.f;
        for (int i = beg + j; i < end; i += 32)
            s += ebuf_csr[(size_t)i * HEADS + h];
        red[t] = s;
    }
    __syncthreads();
    if (t < HEADS) {
        float s = 0.f;
        #pragma unroll
        for (int j = 0; j < 32; j++) s += red[j * 8 + t];
        inv_s[t] = (s > 0.f) ? 1.f / s : 0.f;
    }
    __syncthreads();

    // phase 2: aggregate, 2 groups x 4-way unroll = 8 feat gathers in flight
    int p = t >> 7;          // 0/1 edge group
    int d = t & 127;         // feature dim
    int hh = d >> 4;         // head of this dim
    float inv = inv_s[hh];
    float acc = 0.f;
    int i = beg + p;
    for (; i + 6 < end; i += 8) {
        int s0 = srcs_csr[i],     s1 = srcs_csr[i + 2];
        int s2 = srcs_csr[i + 4], s3 = srcs_csr[i + 6];
        float a0 = ebuf_csr[(size_t)(i)     * HEADS + hh];
        float a1 = ebuf_csr[(size_t)(i + 2) * HEADS + hh];
        float a2 = ebuf_csr[(size_t)(i + 4) * HEADS + hh];
        float a3 = ebuf_csr[(size_t)(i + 6) * HEADS + hh];
        float f0 = bf2f(feat[(size_t)s0 * DIM + d]);
        float f1 = bf2f(feat[(size_t)s1 * DIM + d]);
        float f2 = bf2f(feat[(size_t)s2 * DIM + d]);
        float f3 = bf2f(feat[(size_t)s3 * DIM + d]);
        acc = fmaf(a0, f0, acc);
        acc = fmaf(a1, f1, acc);
        acc = fmaf(a2, f2, acc);
        acc = fmaf(a3, f3, acc);
    }
    for (; i < end; i += 2) {
        int s0 = srcs_csr[i];
        acc = fmaf(ebuf_csr[(size_t)i * HEADS + hh],
                   bf2f(feat[(size_t)s0 * DIM + d]), acc);
    }
    acc *= inv;
    __syncthreads();
    red[t] = acc;
    __syncthreads();
    if (t < 128) {
        float v = red[d] + red[128 + d];
        outp[(size_t)n * DIM + d] = h_in[(size_t)n * ldh + d] + v + bias[d];
    }
}

// ---------------------------------------------------------------- BatchNorm
__global__ __launch_bounds__(128) void bn_stats_kernel(const float* __restrict__ x, int ldx,
                                                       int M, float* __restrict__ stats) {
    int c = threadIdx.x;
    int r0 = blockIdx.x * 128;
    int r1 = min(r0 + 128, M);
    float s = 0.f, sq = 0.f;
    for (int r = r0; r < r1; r++) {
        float v = x[(size_t)r * ldx + c];
        s += v;
        sq = fmaf(v, v, sq);
    }
    atomicAdd(&stats[c], s);
    atomicAdd(&stats[DIM + c], sq);
}

__global__ void bn_apply_kernel(const float* __restrict__ x, int ldin,
                                float* __restrict__ y, int ldout,
                                const float* __restrict__ g, const float* __restrict__ b,
                                const float* __restrict__ stats, int M) {
    int i = blockIdx.x * blockDim.x + threadIdx.x;
    if (i >= M * DIM) return;
    int r = i >> 7, c = i & 127;
    float mu  = stats[c] * (1.f / N_NODES);
    float var = stats[DIM + c] * (1.f / N_NODES) - mu * mu;
    float v = x[(size_t)r * ldin + c];
    y[(size_t)r * ldout + c] = fmaf(g[c] * rsqrtf(var + BN_EPS), v - mu, b[c]);
}

// ---------------------------------------------------------------- decision head
__global__ __launch_bounds__(256) void decide_kernel(
    const float* __restrict__ z, const float* __restrict__ stats,
    const float* __restrict__ g, const float* __restrict__ b,
    const float* __restrict__ W2, float* __restrict__ outp, int M)
{
    int wid = threadIdx.x >> 6, lane = threadIdx.x & 63;
    int n = blockIdx.x * 4 + wid;
    if (n >= M) return;
    float acc = 0.f;
    for (int c = lane; c < DIM; c += 64) {
        float mu  = stats[c] * (1.f / N_NODES);
        float var = stats[DIM + c] * (1.f / N_NODES) - mu * mu;
        float v = fmaf(g[c] * rsqrtf(var + BN_EPS), z[(size_t)n * DIM + c] - mu, b[c]);
        v = fmaxf(v, 0.f);
        acc = fmaf(v, W2[c], acc);
    }
    #pragma unroll
    for (int offs = 32; offs > 0; offs >>= 1)
        acc += __shfl_down(acc, offs);
    if (lane == 0) outp[n] = acc;
}

// ---------------------------------------------------------------- launch
extern "C" void kernel_launch(void* const* d_in, const int* in_sizes, int n_in,
                              void* d_out, int out_size, void* d_ws, size_t ws_size,
                              hipStream_t stream)
{
    const float* x      = (const float*)d_in[0];
    const int*   src    = (const int*)  d_in[1];
    const int*   dst    = (const int*)  d_in[2];
    const float* W_emb  = (const float*)d_in[3];
    const float* b_emb  = (const float*)d_in[4];
    const float* gat_W  = (const float*)d_in[5];
    const float* attn_l = (const float*)d_in[6];
    const float* attn_r = (const float*)d_in[7];
    const float* gat_b  = (const float*)d_in[8];
    const float* bn1_g  = (const float*)d_in[9];
    const float* bn1_b  = (const float*)d_in[10];
    const float* ff_W1  = (const float*)d_in[11];
    const float* ff_b1  = (const float*)d_in[12];
    const float* ff_W2  = (const float*)d_in[13];
    const float* ff_b2  = (const float*)d_in[14];
    const float* bn2_g  = (const float*)d_in[15];
    const float* bn2_b  = (const float*)d_in[16];
    const float* dec_W1 = (const float*)d_in[17];
    const float* dec_bn_g = (const float*)d_in[18];
    const float* dec_bn_b = (const float*)d_in[19];
    const float* dec_W2 = (const float*)d_in[20];
    float* outp = (float*)d_out;

    char* ws = (char*)d_ws;
    size_t off = 0;
    auto alloc = [&](size_t bytes) -> void* {
        void* p = ws + off;
        off += (bytes + 255) & ~(size_t)255;
        return p;
    };
    float* xs    = (float*)alloc((size_t)N_NODES * 512 * 4);
    float* z     = (float*)alloc((size_t)N_NODES * DIM * 4);       // dec gemm out
    unsigned short* featb = (unsigned short*)alloc((size_t)N_NODES * DIM * 2);
    float* el    = (float*)alloc((size_t)N_NODES * HEADS * 4);
    float* er    = (float*)alloc((size_t)N_NODES * HEADS * 4);
    float* ebuf  = (float*)alloc((size_t)N_EDGES * HEADS * 4);
    float* y1    = (float*)alloc((size_t)N_NODES * FF_DIM * 4);
    float* bt    = (float*)alloc((size_t)N_NODES * DIM * 4);
    float* stats = (float*)alloc(2 * DIM * 4);
    int*   counts= (int*)  alloc((size_t)N_NODES * 4);
    int*   indptr= (int*)  alloc((size_t)(N_NODES + 1) * 4);
    int*   cursor= (int*)  alloc((size_t)N_NODES * 4);
    int*   srcs_csr = (int*)alloc((size_t)N_EDGES * 4);
    int*   epos  = (int*)  alloc((size_t)N_EDGES * 4);
    (void)ws_size; (void)in_sizes; (void)n_in; (void)out_size;

    auto launch_gemm = [&](const float* A, int lda, const float* B, int ldb,
                           const float* bias, const float* res, int ldres,
                           float* C, int ldc, int M, int N, int K, int relu,
                           unsigned short* Cbf = nullptr) {
        dim3 grid((N + GBN - 1) / GBN, (M + GBM - 1) / GBM);
        gemm_mfma_kernel<<<grid, 256, 0, stream>>>(A, lda, B, ldb, bias, res, ldres,
                                                   C, ldc, M, N, K, relu, Cbf);
    };

    // ---- CSR build
    hipMemsetAsync(counts, 0, N_NODES * 4, stream);
    hist_kernel<<<(N_EDGES + 255) / 256, 256, 0, stream>>>(dst, counts);
    scan_kernel<<<1, 1024, 0, stream>>>(counts, indptr, N_NODES);
    hipMemcpyAsync(cursor, indptr, N_NODES * 4, hipMemcpyDeviceToDevice, stream);
    scatter_kernel<<<(N_EDGES + 255) / 256, 256, 0, stream>>>(src, dst, cursor, srcs_csr, epos);

    // ---- embed
    launch_gemm(x, IN_DIM, W_emb, DIM, b_emb, nullptr, 0, xs, 512,
                N_NODES, DIM, IN_DIM, 0);

    for (int l = 0; l < LAYERS; l++) {
        const float* h_cur = xs + (size_t)l * DIM;
        // feat (bf16 output)
        launch_gemm(h_cur, 512, gat_W + (size_t)l * DIM * DIM, DIM,
                    nullptr, nullptr, 0, nullptr, DIM, N_NODES, DIM, DIM, 0, featb);
        eler_kernel<<<(N_NODES * HEADS + 255) / 256, 256, 0, stream>>>(
            featb, attn_l + l * DIM, attn_r + l * DIM, el, er);
        edge_exp_kernel<<<(N_EDGES * HEADS + 255) / 256, 256, 0, stream>>>(
            src, dst, epos, el, er, ebuf);
        gat_aggregate_kernel<<<N_NODES, 256, 0, stream>>>(
            featb, ebuf, indptr, srcs_csr, h_cur, 512, gat_b + l * DIM, bt);
        hipMemsetAsync(stats, 0, 2 * DIM * 4, stream);
        bn_stats_kernel<<<(N_NODES + 127) / 128, 128, 0, stream>>>(bt, DIM, N_NODES, stats);
        bn_apply_kernel<<<(N_NODES * DIM + 255) / 256, 256, 0, stream>>>(
            bt, DIM, bt, DIM, bn1_g + l * DIM, bn1_b + l * DIM, stats, N_NODES);
        launch_gemm(bt, DIM, ff_W1 + (size_t)l * DIM * FF_DIM, FF_DIM,
                    ff_b1 + l * FF_DIM, nullptr, 0, y1, FF_DIM,
                    N_NODES, FF_DIM, DIM, 1);
        launch_gemm(y1, FF_DIM, ff_W2 + (size_t)l * FF_DIM * DIM, DIM,
                    ff_b2 + l * DIM, bt, DIM, bt, DIM,
                    N_NODES, DIM, FF_DIM, 0);
        hipMemsetAsync(stats, 0, 2 * DIM * 4, stream);
        bn_stats_kernel<<<(N_NODES + 127) / 128, 128, 0, stream>>>(bt, DIM, N_NODES, stats);
        bn_apply_kernel<<<(N_NODES * DIM + 255) / 256, 256, 0, stream>>>(
            bt, DIM, xs + (size_t)(l + 1) * DIM, 512,
            bn2_g + l * DIM, bn2_b + l * DIM, stats, N_NODES);
    }

    // ---- decision head
    launch_gemm(xs, 512, dec_W1, DIM, nullptr, nullptr, 0, z, DIM,
                N_NODES, DIM, 4 * DIM, 0);
    hipMemsetAsync(stats, 0, 2 * DIM * 4, stream);
    bn_stats_kernel<<<(N_NODES + 127) / 128, 128, 0, stream>>>(z, DIM, N_NODES, stats);
    decide_kernel<<<(N_NODES + 3) / 4, 256, 0, stream>>>(
        z, stats, dec_bn_g, dec_bn_b, dec_W2, outp, N_NODES);
}